// Round 12
// baseline (164.575 us; speedup 1.0000x reference)
//
#include <hip/hip_runtime.h>
#include <hip/hip_bf16.h>

#define B_ 2
#define N_ 2048
#define C_ 1024
#define H_ 16
#define HD_ 64

#define KT 64            // key tile width per flash iteration
#define NT (N_ / KT)     // 32 tiles
#define TILE_E 4096      // elems per staged tile (64x64 bf16 = 8KB)
#define PSTR 72          // P LDS row stride (fallback kernel)
#define NW 8             // waves per block (fallback kernel)
#define QB 128           // q rows per block (fallback kernel)

#define NWM 8            // waves per block (main kernel: 512 threads)
#define QBM 128          // q rows per block (main: 16 per wave)

typedef short s16x8 __attribute__((ext_vector_type(8)));
typedef short s16x4 __attribute__((ext_vector_type(4)));
typedef float f32x4 __attribute__((ext_vector_type(4)));

__device__ __forceinline__ s16x8 cvt8(float4 a, float4 b) {
    union { s16x8 v; __hip_bfloat162 h[4]; } u;
    u.h[0] = __float22bfloat162_rn(float2{a.x, a.y});
    u.h[1] = __float22bfloat162_rn(float2{a.z, a.w});
    u.h[2] = __float22bfloat162_rn(float2{b.x, b.y});
    u.h[3] = __float22bfloat162_rn(float2{b.z, b.w});
    return u.v;
}

// async 16B/lane global -> LDS (DMA, no VGPR round trip)
__device__ __forceinline__ void gll16(const void* g, void* l) {
    __builtin_amdgcn_global_load_lds(
        (const __attribute__((address_space(1))) unsigned*)g,
        (__attribute__((address_space(3))) unsigned*)l, 16, 0, 0);
}

// ---- standalone pack_mask kept for the fallback path only
__global__ __launch_bounds__(256)
void pack_mask(const int* __restrict__ M, unsigned long long* __restrict__ bits) {
    const int gw   = (blockIdx.x * 256 + threadIdx.x) >> 6;
    const int lane = threadIdx.x & 63;
#pragma unroll
    for (int it = 0; it < 16; ++it) {
        const size_t wi = (size_t)gw * 16 + it;
        unsigned long long bal = __ballot(M[wi * 64 + lane] != 0);
        if (lane == 0) bits[wi] = bal;
    }
}

// ---- fused prepass: mask pack (blocks 0..2047), conv_k (2048..4095),
//      conv_v (4096..4607).
__global__ __launch_bounds__(256)
void prepass(const int* __restrict__ M, const float* __restrict__ K,
             const float* __restrict__ V, unsigned long long* __restrict__ bits,
             ushort* __restrict__ Kw, ushort* __restrict__ Vw) {
    const int bid = blockIdx.x;
    const int tid = threadIdx.x;
    if (bid < 2048) {
        // vectorized mask pack: 16 ints/thread (4x int4 = 64B), 1 ushort out.
        const int gt = bid * 256 + tid;            // 0..524287
        const int4* src = (const int4*)M + (size_t)gt * 4;
        unsigned r = 0;
#pragma unroll
        for (int c = 0; c < 4; ++c) {
            const int4 m4 = src[c];
            r |= (m4.x != 0 ? 1u : 0u) << (c * 4 + 0);
            r |= (m4.y != 0 ? 1u : 0u) << (c * 4 + 1);
            r |= (m4.z != 0 ? 1u : 0u) << (c * 4 + 2);
            r |= (m4.w != 0 ? 1u : 0u) << (c * 4 + 3);
        }
        ((ushort*)bits)[gt] = (ushort)r;
    } else if (bid < 4096) {
        // K fp32 -> bf16, tile-major, KEY-PERMUTED rows (aligns QK^T output
        // layout with the PV A-fragment layout so P stays in registers),
        // d-block XOR swizzle baked in.
        // perm: tile row p for key k: p5=k5, p4=k2, p3p2=k4k3, p1p0=k1k0
        const int gt = (bid - 2048) * 256 + tid;
        const int b  = gt >> 18;
        const int h  = (gt >> 14) & 15;
        const int n  = (gt >> 3) & 2047;
        const int db = gt & 7;
        const size_t src = (size_t)(b * N_ + n) * C_ + h * 64 + db * 8;
        float4 f0 = *(const float4*)(K + src);
        float4 f1 = *(const float4*)(K + src + 4);
        const int key = n & 63, kt = n >> 6;
        const int p = (key & 32) | ((key & 4) << 2) | ((key >> 1) & 12) | (key & 3);
        ushort* dst = Kw + (size_t)((b * H_ + h) * NT + kt) * TILE_E
                         + p * 64 + ((db ^ (p & 7)) * 8);
        *(s16x8*)dst = cvt8(f0, f1);
    } else {
        // V fp32 -> bf16 TRANSPOSED, tile-major, TRUE key order,
        // key-block XOR swizzle.
        const int gt  = (bid - 4096) * 256 + tid;
        const int b   = gt >> 16;
        const int h   = (gt >> 12) & 15;
        const int kt  = (gt >> 7) & 31;
        const int kb4 = (gt >> 3) & 15;
        const int db  = gt & 7;
        const int key0 = kb4 * 4;
        float f[4][8];
#pragma unroll
        for (int i = 0; i < 4; ++i) {
            const size_t src = (size_t)(b * N_ + kt * 64 + key0 + i) * C_ + h * 64 + db * 8;
            *(float4*)&f[i][0] = *(const float4*)(V + src);
            *(float4*)&f[i][4] = *(const float4*)(V + src + 4);
        }
        ushort* tb = Vw + (size_t)((b * H_ + h) * NT + kt) * TILE_E;
#pragma unroll
        for (int j = 0; j < 8; ++j) {
            const int d = db * 8 + j;
            union { s16x4 v; __hip_bfloat162 h2[2]; } u;
            u.h2[0] = __float22bfloat162_rn(float2{f[0][j], f[1][j]});
            u.h2[1] = __float22bfloat162_rn(float2{f[2][j], f[3][j]});
            *(s16x4*)(tb + d * 64 + (((key0 >> 3) ^ (d & 7)) * 8) + (key0 & 7)) = u.v;
        }
    }
}

// ---- main: R11 structure (512 threads, 8 waves, shared staging DMA,
//      16 q/wave, in-register P, ones-trick sums), micro-tuned:
//      (1) no s_setprio (hurts barrier-locked multiwave, m190);
//      (2) exp2 decoupled from mask (select applied to exp2 OUTPUT).
__global__ __launch_bounds__(512, 2)
void mha_fwd(const float* __restrict__ Q, const ushort* __restrict__ Kw,
             const ushort* __restrict__ Vw, const unsigned* __restrict__ bits,
             float* __restrict__ O) {
    __shared__ ushort Kl[2][TILE_E];       // 16 KB
    __shared__ ushort Vt[2][TILE_E];       // 16 KB  -> 32768 B total

    // XCD-aware bijective decode: xcd = sid&7 owns heads 4*xcd..4*xcd+3
    const int sid = blockIdx.x;            // 0..511
    const int jj  = sid >> 3;              // 0..63
    const int hb  = ((sid & 7) << 2) | (jj & 3);   // 0..31 = b*16+h
    const int qt  = jj >> 2;                        // 0..15
    const int h   = hb & 15;
    const int b   = hb >> 4;

    const int tid  = threadIdx.x;          // 0..511
    const int w    = tid >> 6;             // wave 0..7
    const int lane = tid & 63;
    const int l16  = lane & 15;
    const int quad = lane >> 4;

    const size_t head_off = (size_t)b * N_ * C_ + (size_t)h * HD_;
    const int qb = qt * QBM + w * 16;

    // Q fragment (B-operand of S^T = K Q^T); fold 1/8*log2(e): log2-domain
    const float qs = 0.125f * 1.44269504088896f;
    const size_t qoff = head_off + (size_t)(qb + l16) * C_ + quad * 8;
    float4 q0 = *(const float4*)(Q + qoff);
    float4 q1 = *(const float4*)(Q + qoff + 4);
    float4 q2 = *(const float4*)(Q + qoff + 32);
    float4 q3 = *(const float4*)(Q + qoff + 36);
    q0.x*=qs; q0.y*=qs; q0.z*=qs; q0.w*=qs;
    q1.x*=qs; q1.y*=qs; q1.z*=qs; q1.w*=qs;
    q2.x*=qs; q2.y*=qs; q2.z*=qs; q2.w*=qs;
    q3.x*=qs; q3.y*=qs; q3.z*=qs; q3.w*=qs;
    const s16x8 qa0 = cvt8(q0, q1);
    const s16x8 qa1 = cvt8(q2, q3);

    // constant all-ones bf16 B-fragment: row-sum via MFMA (ones-trick)
    s16x8 onesb;
#pragma unroll
    for (int i = 0; i < 8; ++i) onesb[i] = (short)0x3F80;

    // loop-invariant zero C-tuple: avoids re-zeroing z each subtile
    const f32x4 kZero = {0.f, 0.f, 0.f, 0.f};

    f32x4 acc[4];
#pragma unroll
    for (int c = 0; c < 4; ++c) acc[c] = f32x4{0.f, 0.f, 0.f, 0.f};
    f32x4 sum = f32x4{0.f, 0.f, 0.f, 0.f};

    // hoisted fragment element base (loop-invariant)
    const int fbase = l16 * 64 + ((quad ^ (l16 & 7)) * 8);

    // staging pointers: 512 threads cover an 8KB tile in ONE 16B/lane round
    const size_t tilebase = (size_t)((b * H_ + h) * NT) * TILE_E;
    const ushort* Kg = Kw + tilebase + (size_t)tid * 8;
    const ushort* Vg = Vw + tilebase + (size_t)tid * 8;

    const unsigned* mq = bits + ((size_t)b * N_ + qb + l16) * (N_ / 32);

    // issue tile 0 into buffer 0 (drained by first barrier)
    gll16(Kg, &Kl[0][w * 512]);
    gll16(Vg, &Vt[0][w * 512]);
    const ushort* Kg_pf = Kg + TILE_E;
    const ushort* Vg_pf = Vg + TILE_E;

    uint4 mw = *(const uint4*)mq;  mq += 4;   // mask words for first tile pair

    for (int kt2 = 0; kt2 < NT; kt2 += 2) {
        const bool pf1 = (kt2 + 2 < NT);
        // prefetch next pair's mask words (guarded: never reads past bits)
        uint4 mw_nxt = mw;
        if (pf1) { mw_nxt = *(const uint4*)mq; }
        mq += 4;
#pragma unroll
        for (int u = 0; u < 2; ++u) {        // u == buffer index (compile-time)
            __syncthreads();   // tile staged; all waves done reading other buf
            if (u == 0 || pf1) {             // prefetch next tile into other buf
                gll16(Kg_pf, &Kl[1 - u][w * 512]);
                gll16(Vg_pf, &Vt[1 - u][w * 512]);
                Kg_pf += TILE_E;  Vg_pf += TILE_E;
            }
            const unsigned w0 = u ? mw.z : mw.x;
            const unsigned w1 = u ? mw.w : mw.y;

            // S^T = K Q^T on the PERMUTED key rows: position (t,quad,r) holds
            // key 32*(t>>1) + 8*quad + 4*(t&1) + r  == PV A-fragment order.
            f32x4 s[4];
#pragma unroll
            for (int t = 0; t < 4; ++t) {
                s16x8 kb0 = *(const s16x8*)(&Kl[u][fbase + t * 1024]);
                s16x8 kb1 = *(const s16x8*)(&Kl[u][(fbase ^ 32) + t * 1024]);
                f32x4 z = __builtin_amdgcn_mfma_f32_16x16x32_bf16(kb0, qa0, kZero, 0, 0, 0);
                z = __builtin_amdgcn_mfma_f32_16x16x32_bf16(kb1, qa1, z, 0, 0, 0);
                s[t] = z;
            }

            // softmax (unnormalized). exp2 issues immediately; the mask select
            // is applied to the OUTPUT (p = bit ? e : 0), so the 4-cyc TRANS
            // op never waits on the bit-extract chain. exp2(-1e9)==0 semantics
            // preserved exactly.
            const unsigned aw0 = w0 >> (quad * 8);   // t=0 (lo nibble) / t=1 (hi)
            const unsigned aw1 = w1 >> (quad * 8);   // t=2 / t=3
            union { s16x8 v; __hip_bfloat162 h2[4]; } pk0, pk1;
#pragma unroll
            for (int t = 0; t < 4; ++t) {
                const unsigned aw = ((t < 2) ? aw0 : aw1) >> ((t & 1) * 4);
                const float e0 = __builtin_amdgcn_exp2f(s[t][0]);
                const float e1 = __builtin_amdgcn_exp2f(s[t][1]);
                const float e2 = __builtin_amdgcn_exp2f(s[t][2]);
                const float e3 = __builtin_amdgcn_exp2f(s[t][3]);
                const float p0 = ((aw >> 0) & 1u) ? e0 : 0.0f;
                const float p1 = ((aw >> 1) & 1u) ? e1 : 0.0f;
                const float p2 = ((aw >> 2) & 1u) ? e2 : 0.0f;
                const float p3 = ((aw >> 3) & 1u) ? e3 : 0.0f;
                __hip_bfloat162 lo = __float22bfloat162_rn(float2{p0, p1});
                __hip_bfloat162 hi = __float22bfloat162_rn(float2{p2, p3});
                if      (t == 0) { pk0.h2[0] = lo; pk0.h2[1] = hi; }
                else if (t == 1) { pk0.h2[2] = lo; pk0.h2[3] = hi; }
                else if (t == 2) { pk1.h2[0] = lo; pk1.h2[1] = hi; }
                else             { pk1.h2[2] = lo; pk1.h2[3] = hi; }
            }

            // PV + ones-sum: P is already the A-fragment, fully in-register.
#pragma unroll
            for (int half = 0; half < 2; ++half) {
                const s16x8 pa = half ? pk1.v : pk0.v;
#pragma unroll
                for (int c = 0; c < 4; ++c) {
                    const int vidx = (half ? (fbase ^ 32) : fbase) + c * 1024;
                    s16x8 vb = *(const s16x8*)(&Vt[u][vidx]);
                    acc[c] = __builtin_amdgcn_mfma_f32_16x16x32_bf16(pa, vb, acc[c], 0, 0, 0);
                }
                sum = __builtin_amdgcn_mfma_f32_16x16x32_bf16(pa, onesb, sum, 0, 0, 0);
            }
        }
        mw = mw_nxt;
    }

    // epilogue: row sums are lane-local (ones-trick), no shuffles needed
#pragma unroll
    for (int r = 0; r < 4; ++r) {
        const float inv = 1.0f / sum[r];
        const size_t obase = head_off + (size_t)(qb + quad * 4 + r) * C_;
        O[obase + l16]      = acc[0][r] * inv;
        O[obase + l16 + 16] = acc[1][r] * inv;
        O[obase + l16 + 32] = acc[2][r] * inv;
        O[obase + l16 + 48] = acc[3][r] * inv;
    }
}

// ================== fallback (R6 verbatim): used if ws_size too small =========
#define KSTR 72
#define VSTR 72
__global__ __launch_bounds__(512, 4)
void mha_fwd_fb(const float* __restrict__ Q, const float* __restrict__ K,
                const float* __restrict__ V, const unsigned* __restrict__ bits,
                float* __restrict__ O) {
    __shared__ ushort Kl[2][KT * KSTR];
    __shared__ ushort Vt[2][HD_ * VSTR];
    __shared__ ushort Pl[NW][16 * PSTR];
    const int qt = blockIdx.x, h = blockIdx.y, b = blockIdx.z, tid = threadIdx.x;
    const int w = tid >> 6, lane = tid & 63, l16 = lane & 15, quad = lane >> 4;
    const size_t head_off = (size_t)b * N_ * C_ + (size_t)h * HD_;
    const int qb = qt * QB + w * 16;
    const float qs = 0.125f * 1.44269504088896f;
    const size_t qoff = head_off + (size_t)(qb + l16) * C_ + quad * 8;
    float4 q0 = *(const float4*)(Q + qoff);
    float4 q1 = *(const float4*)(Q + qoff + 4);
    float4 q2 = *(const float4*)(Q + qoff + 32);
    float4 q3 = *(const float4*)(Q + qoff + 36);
    q0.x*=qs; q0.y*=qs; q0.z*=qs; q0.w*=qs;
    q1.x*=qs; q1.y*=qs; q1.z*=qs; q1.w*=qs;
    q2.x*=qs; q2.y*=qs; q2.z*=qs; q2.w*=qs;
    q3.x*=qs; q3.y*=qs; q3.z*=qs; q3.w*=qs;
    const s16x8 qa0 = cvt8(q0, q1);
    const s16x8 qa1 = cvt8(q2, q3);
    f32x4 acc[4];
#pragma unroll
    for (int c = 0; c < 4; ++c) acc[c] = f32x4{0.f, 0.f, 0.f, 0.f};
    float lsum = 0.f;
    const int skey = tid >> 3, sd0 = (tid & 7) * 8;
    const int kp = tid >> 4, vd0 = (tid & 15) * 4;
    const int vcol = 2 * (kp & 3) + ((((kp >> 2) ^ (vd0 >> 3)) & 7) << 3);
    const unsigned* brow = bits + ((size_t)b * N_ + qb + l16) * (N_ / 32);
    const float SHIFT = 16.0f;
    {
        const size_t kbase = head_off + (size_t)skey * C_ + sd0;
        float4 kA = *(const float4*)(K + kbase);
        float4 kB = *(const float4*)(K + kbase + 4);
        *(s16x8*)(&Kl[0][skey * KSTR + sd0]) = cvt8(kA, kB);
        const size_t vbase = head_off + (size_t)(2 * kp) * C_ + vd0;
        float4 vA = *(const float4*)(V + vbase);
        float4 vB = *(const float4*)(V + vbase + C_);
        const float* ap = (const float*)&vA;
        const float* bp = (const float*)&vB;
#pragma unroll
        for (int i = 0; i < 4; ++i) {
            __hip_bfloat162 pr = __float22bfloat162_rn(float2{ap[i], bp[i]});
            *(unsigned*)(&Vt[0][(vd0 + i) * VSTR + vcol]) = *(unsigned*)&pr;
        }
    }
    for (int kt = 0; kt < NT; ++kt) {
        const int cur = kt & 1;
        float4 kA, kB, vA, vB;
        const bool has_next = (kt + 1 < NT);
        if (has_next) {
            const size_t kbase = head_off + (size_t)((kt + 1) * KT + skey) * C_ + sd0;
            kA = *(const float4*)(K + kbase);
            kB = *(const float4*)(K + kbase + 4);
            const size_t vbase = head_off + (size_t)((kt + 1) * KT + 2 * kp) * C_ + vd0;
            vA = *(const float4*)(V + vbase);
            vB = *(const float4*)(V + vbase + C_);
        }
        const unsigned w0 = brow[2 * kt];
        const unsigned w1 = brow[2 * kt + 1];
        __syncthreads();
        f32x4 s[4];
#pragma unroll
        for (int t = 0; t < 4; ++t) {
            s16x8 kb0 = *(const s16x8*)(&Kl[cur][(t * 16 + l16) * KSTR + quad * 8]);
            s16x8 kb1 = *(const s16x8*)(&Kl[cur][(t * 16 + l16) * KSTR + quad * 8 + 32]);
            f32x4 z = {0.f, 0.f, 0.f, 0.f};
            z = __builtin_amdgcn_mfma_f32_16x16x32_bf16(kb0, qa0, z, 0, 0, 0);
            z = __builtin_amdgcn_mfma_f32_16x16x32_bf16(kb1, qa1, z, 0, 0, 0);
            s[t] = z;
        }
        const unsigned a0 = w0 >> (quad * 4);
        const unsigned a1 = w1 >> (quad * 4);
#pragma unroll
        for (int t = 0; t < 4; ++t) {
            const unsigned aw = (t < 2) ? a0 : a1;
            const int sh = (t & 1) * 16;
            float p0 = exp2f((((aw >> (sh + 0)) & 1u) ? s[t][0] : -1e9f) - SHIFT);
            float p1 = exp2f((((aw >> (sh + 1)) & 1u) ? s[t][1] : -1e9f) - SHIFT);
            float p2 = exp2f((((aw >> (sh + 2)) & 1u) ? s[t][2] : -1e9f) - SHIFT);
            float p3 = exp2f((((aw >> (sh + 3)) & 1u) ? s[t][3] : -1e9f) - SHIFT);
            lsum += (p0 + p1) + (p2 + p3);
            union { s16x4 v; __hip_bfloat162 h2[2]; } uu;
            uu.h2[0] = __float22bfloat162_rn(float2{p0, p1});
            uu.h2[1] = __float22bfloat162_rn(float2{p2, p3});
            *(s16x4*)(&Pl[w][l16 * PSTR + t * 16 + quad * 4]) = uu.v;
        }
#pragma unroll
        for (int half = 0; half < 2; ++half) {
            s16x8 pa = *(const s16x8*)(&Pl[w][l16 * PSTR + half * 32 + quad * 8]);
#pragma unroll
            for (int c = 0; c < 4; ++c) {
                const int dr = c * 16 + l16;
                const int blk = (half * 4 + quad) ^ ((dr >> 3) & 7);
                s16x8 vb = *(const s16x8*)(&Vt[cur][dr * VSTR + blk * 8]);
                acc[c] = __builtin_amdgcn_mfma_f32_16x16x32_bf16(pa, vb, acc[c], 0, 0, 0);
            }
        }
        if (has_next) {
            *(s16x8*)(&Kl[1 - cur][skey * KSTR + sd0]) = cvt8(kA, kB);
            const float* ap = (const float*)&vA;
            const float* bp = (const float*)&vB;
#pragma unroll
            for (int i = 0; i < 4; ++i) {
                __hip_bfloat162 pr = __float22bfloat162_rn(float2{ap[i], bp[i]});
                *(unsigned*)(&Vt[1 - cur][(vd0 + i) * VSTR + vcol]) = *(unsigned*)&pr;
            }
        }
    }
    lsum += __shfl_xor(lsum, 16);
    lsum += __shfl_xor(lsum, 32);
#pragma unroll
    for (int r = 0; r < 4; ++r) {
        const float inv = 1.0f / __shfl(lsum, quad * 4 + r);
        const size_t obase = head_off + (size_t)(qb + quad * 4 + r) * C_;
        O[obase + l16]      = acc[0][r] * inv;
        O[obase + l16 + 16] = acc[1][r] * inv;
        O[obase + l16 + 32] = acc[2][r] * inv;
        O[obase + l16 + 48] = acc[3][r] * inv;
    }
}

extern "C" void kernel_launch(void* const* d_in, const int* in_sizes, int n_in,
                              void* d_out, int out_size, void* d_ws, size_t ws_size,
                              hipStream_t stream) {
    const float* q = (const float*)d_in[0];
    const float* k = (const float*)d_in[1];
    const float* v = (const float*)d_in[2];
    const int*   m = (const int*)d_in[3];
    float*       o = (float*)d_out;

    const size_t BITS_BYTES = (size_t)B_ * N_ * N_ / 8;          // 1 MiB
    const size_t KV_BYTES   = (size_t)B_ * H_ * N_ * HD_ * 2;    // 8.39 MB each
    const size_t NEED       = BITS_BYTES + 2 * KV_BYTES;

    unsigned long long* bits = (unsigned long long*)d_ws;

    if (ws_size >= NEED) {
        ushort* kw = (ushort*)((char*)d_ws + BITS_BYTES);
        ushort* vw = (ushort*)((char*)d_ws + BITS_BYTES + KV_BYTES);
        hipLaunchKernelGGL(prepass, dim3(4608), dim3(256), 0, stream,
                           m, k, v, bits, kw, vw);
        hipLaunchKernelGGL(mha_fwd, dim3(512), dim3(512), 0, stream,
                           q, kw, vw, (const unsigned*)bits, o);
    } else {
        hipLaunchKernelGGL(pack_mask, dim3(2048), dim3(256), 0, stream, m, bits);
        dim3 grid(N_ / QB, H_, B_);
        hipLaunchKernelGGL(mha_fwd_fb, grid, dim3(512), 0, stream,
                           q, k, v, (const unsigned*)bits, o);
    }
}

// Round 13
// 162.704 us; speedup vs baseline: 1.0115x; 1.0115x over previous
//
#include <hip/hip_runtime.h>
#include <hip/hip_bf16.h>

#define B_ 2
#define N_ 2048
#define C_ 1024
#define H_ 16
#define HD_ 64

#define KT 64            // key tile width per flash iteration
#define NT (N_ / KT)     // 32 tiles
#define TILE_E 4096      // elems per staged tile (64x64 bf16 = 8KB)
#define PSTR 72          // P LDS row stride (fallback kernel)
#define NW 8             // waves per block (fallback kernel)
#define QB 128           // q rows per block (fallback kernel)

#define NWM 8            // waves per block (main kernel: 512 threads)
#define QBM 128          // q rows per block (main: 16 per wave)

typedef short s16x8 __attribute__((ext_vector_type(8)));
typedef short s16x4 __attribute__((ext_vector_type(4)));
typedef float f32x4 __attribute__((ext_vector_type(4)));

__device__ __forceinline__ s16x8 cvt8(float4 a, float4 b) {
    union { s16x8 v; __hip_bfloat162 h[4]; } u;
    u.h[0] = __float22bfloat162_rn(float2{a.x, a.y});
    u.h[1] = __float22bfloat162_rn(float2{a.z, a.w});
    u.h[2] = __float22bfloat162_rn(float2{b.x, b.y});
    u.h[3] = __float22bfloat162_rn(float2{b.z, b.w});
    return u.v;
}

// async 16B/lane global -> LDS (DMA, no VGPR round trip)
__device__ __forceinline__ void gll16(const void* g, void* l) {
    __builtin_amdgcn_global_load_lds(
        (const __attribute__((address_space(1))) unsigned*)g,
        (__attribute__((address_space(3))) unsigned*)l, 16, 0, 0);
}

// ---- standalone pack_mask kept for the fallback path only
__global__ __launch_bounds__(256)
void pack_mask(const int* __restrict__ M, unsigned long long* __restrict__ bits) {
    const int gw   = (blockIdx.x * 256 + threadIdx.x) >> 6;
    const int lane = threadIdx.x & 63;
#pragma unroll
    for (int it = 0; it < 16; ++it) {
        const size_t wi = (size_t)gw * 16 + it;
        unsigned long long bal = __ballot(M[wi * 64 + lane] != 0);
        if (lane == 0) bits[wi] = bal;
    }
}

// ---- fused prepass: mask pack (blocks 0..2047), conv_k (2048..4095),
//      conv_v (4096..4607).
__global__ __launch_bounds__(256)
void prepass(const int* __restrict__ M, const float* __restrict__ K,
             const float* __restrict__ V, unsigned long long* __restrict__ bits,
             ushort* __restrict__ Kw, ushort* __restrict__ Vw) {
    const int bid = blockIdx.x;
    const int tid = threadIdx.x;
    if (bid < 2048) {
        // vectorized mask pack: 16 ints/thread (4x int4 = 64B), 1 ushort out.
        const int gt = bid * 256 + tid;            // 0..524287
        const int4* src = (const int4*)M + (size_t)gt * 4;
        unsigned r = 0;
#pragma unroll
        for (int c = 0; c < 4; ++c) {
            const int4 m4 = src[c];
            r |= (m4.x != 0 ? 1u : 0u) << (c * 4 + 0);
            r |= (m4.y != 0 ? 1u : 0u) << (c * 4 + 1);
            r |= (m4.z != 0 ? 1u : 0u) << (c * 4 + 2);
            r |= (m4.w != 0 ? 1u : 0u) << (c * 4 + 3);
        }
        ((ushort*)bits)[gt] = (ushort)r;
    } else if (bid < 4096) {
        // K fp32 -> bf16, tile-major, KEY-PERMUTED rows (aligns QK^T output
        // layout with the PV A-fragment layout so P stays in registers),
        // d-block XOR swizzle baked in.
        // perm: tile row p for key k: p5=k5, p4=k2, p3p2=k4k3, p1p0=k1k0
        const int gt = (bid - 2048) * 256 + tid;
        const int b  = gt >> 18;
        const int h  = (gt >> 14) & 15;
        const int n  = (gt >> 3) & 2047;
        const int db = gt & 7;
        const size_t src = (size_t)(b * N_ + n) * C_ + h * 64 + db * 8;
        float4 f0 = *(const float4*)(K + src);
        float4 f1 = *(const float4*)(K + src + 4);
        const int key = n & 63, kt = n >> 6;
        const int p = (key & 32) | ((key & 4) << 2) | ((key >> 1) & 12) | (key & 3);
        ushort* dst = Kw + (size_t)((b * H_ + h) * NT + kt) * TILE_E
                         + p * 64 + ((db ^ (p & 7)) * 8);
        *(s16x8*)dst = cvt8(f0, f1);
    } else {
        // V fp32 -> bf16 TRANSPOSED, tile-major, TRUE key order,
        // key-block XOR swizzle.
        const int gt  = (bid - 4096) * 256 + tid;
        const int b   = gt >> 16;
        const int h   = (gt >> 12) & 15;
        const int kt  = (gt >> 7) & 31;
        const int kb4 = (gt >> 3) & 15;
        const int db  = gt & 7;
        const int key0 = kb4 * 4;
        float f[4][8];
#pragma unroll
        for (int i = 0; i < 4; ++i) {
            const size_t src = (size_t)(b * N_ + kt * 64 + key0 + i) * C_ + h * 64 + db * 8;
            *(float4*)&f[i][0] = *(const float4*)(V + src);
            *(float4*)&f[i][4] = *(const float4*)(V + src + 4);
        }
        ushort* tb = Vw + (size_t)((b * H_ + h) * NT + kt) * TILE_E;
#pragma unroll
        for (int j = 0; j < 8; ++j) {
            const int d = db * 8 + j;
            union { s16x4 v; __hip_bfloat162 h2[2]; } u;
            u.h2[0] = __float22bfloat162_rn(float2{f[0][j], f[1][j]});
            u.h2[1] = __float22bfloat162_rn(float2{f[2][j], f[3][j]});
            *(s16x4*)(tb + d * 64 + (((key0 >> 3) ^ (d & 7)) * 8) + (key0 & 7)) = u.v;
        }
    }
}

// ---- main: R11-exact (best measured: 59.2 us). 512-thread blocks, 8 waves,
//      ONE staging DMA serves 8 waves, 2 blocks/CU, 16 q/wave, in-register P,
//      ones-trick sums, setprio around MFMA clusters, masked-exp2 softmax.
__global__ __launch_bounds__(512, 2)
void mha_fwd(const float* __restrict__ Q, const ushort* __restrict__ Kw,
             const ushort* __restrict__ Vw, const unsigned* __restrict__ bits,
             float* __restrict__ O) {
    __shared__ ushort Kl[2][TILE_E];       // 16 KB
    __shared__ ushort Vt[2][TILE_E];       // 16 KB  -> 32768 B total

    // XCD-aware bijective decode: xcd = sid&7 owns heads 4*xcd..4*xcd+3
    const int sid = blockIdx.x;            // 0..511
    const int jj  = sid >> 3;              // 0..63
    const int hb  = ((sid & 7) << 2) | (jj & 3);   // 0..31 = b*16+h
    const int qt  = jj >> 2;                        // 0..15
    const int h   = hb & 15;
    const int b   = hb >> 4;

    const int tid  = threadIdx.x;          // 0..511
    const int w    = tid >> 6;             // wave 0..7
    const int lane = tid & 63;
    const int l16  = lane & 15;
    const int quad = lane >> 4;

    const size_t head_off = (size_t)b * N_ * C_ + (size_t)h * HD_;
    const int qb = qt * QBM + w * 16;

    // Q fragment (B-operand of S^T = K Q^T); fold 1/8*log2(e): log2-domain
    const float qs = 0.125f * 1.44269504088896f;
    const size_t qoff = head_off + (size_t)(qb + l16) * C_ + quad * 8;
    float4 q0 = *(const float4*)(Q + qoff);
    float4 q1 = *(const float4*)(Q + qoff + 4);
    float4 q2 = *(const float4*)(Q + qoff + 32);
    float4 q3 = *(const float4*)(Q + qoff + 36);
    q0.x*=qs; q0.y*=qs; q0.z*=qs; q0.w*=qs;
    q1.x*=qs; q1.y*=qs; q1.z*=qs; q1.w*=qs;
    q2.x*=qs; q2.y*=qs; q2.z*=qs; q2.w*=qs;
    q3.x*=qs; q3.y*=qs; q3.z*=qs; q3.w*=qs;
    const s16x8 qa0 = cvt8(q0, q1);
    const s16x8 qa1 = cvt8(q2, q3);

    // constant all-ones bf16 B-fragment: row-sum via MFMA (ones-trick)
    s16x8 onesb;
#pragma unroll
    for (int i = 0; i < 8; ++i) onesb[i] = (short)0x3F80;

    // loop-invariant zero C-tuple: avoids re-zeroing z each subtile
    const f32x4 kZero = {0.f, 0.f, 0.f, 0.f};

    f32x4 acc[4];
#pragma unroll
    for (int c = 0; c < 4; ++c) acc[c] = f32x4{0.f, 0.f, 0.f, 0.f};
    f32x4 sum = f32x4{0.f, 0.f, 0.f, 0.f};

    // hoisted fragment element base (loop-invariant)
    const int fbase = l16 * 64 + ((quad ^ (l16 & 7)) * 8);

    // staging pointers: 512 threads cover an 8KB tile in ONE 16B/lane round
    const size_t tilebase = (size_t)((b * H_ + h) * NT) * TILE_E;
    const ushort* Kg = Kw + tilebase + (size_t)tid * 8;
    const ushort* Vg = Vw + tilebase + (size_t)tid * 8;

    const unsigned* mq = bits + ((size_t)b * N_ + qb + l16) * (N_ / 32);

    // issue tile 0 into buffer 0 (drained by first barrier)
    gll16(Kg, &Kl[0][w * 512]);
    gll16(Vg, &Vt[0][w * 512]);
    const ushort* Kg_pf = Kg + TILE_E;
    const ushort* Vg_pf = Vg + TILE_E;

    uint4 mw = *(const uint4*)mq;  mq += 4;   // mask words for first tile pair

    for (int kt2 = 0; kt2 < NT; kt2 += 2) {
        const bool pf1 = (kt2 + 2 < NT);
        // prefetch next pair's mask words (guarded: never reads past bits)
        uint4 mw_nxt = mw;
        if (pf1) { mw_nxt = *(const uint4*)mq; }
        mq += 4;
#pragma unroll
        for (int u = 0; u < 2; ++u) {        // u == buffer index (compile-time)
            __syncthreads();   // tile staged; all waves done reading other buf
            if (u == 0 || pf1) {             // prefetch next tile into other buf
                gll16(Kg_pf, &Kl[1 - u][w * 512]);
                gll16(Vg_pf, &Vt[1 - u][w * 512]);
                Kg_pf += TILE_E;  Vg_pf += TILE_E;
            }
            const unsigned w0 = u ? mw.z : mw.x;
            const unsigned w1 = u ? mw.w : mw.y;

            // S^T = K Q^T on the PERMUTED key rows: position (t,quad,r) holds
            // key 32*(t>>1) + 8*quad + 4*(t&1) + r  == PV A-fragment order.
            f32x4 s[4];
            __builtin_amdgcn_s_setprio(1);
#pragma unroll
            for (int t = 0; t < 4; ++t) {
                s16x8 kb0 = *(const s16x8*)(&Kl[u][fbase + t * 1024]);
                s16x8 kb1 = *(const s16x8*)(&Kl[u][(fbase ^ 32) + t * 1024]);
                f32x4 z = __builtin_amdgcn_mfma_f32_16x16x32_bf16(kb0, qa0, kZero, 0, 0, 0);
                z = __builtin_amdgcn_mfma_f32_16x16x32_bf16(kb1, qa1, z, 0, 0, 0);
                s[t] = z;
            }
            __builtin_amdgcn_s_setprio(0);

            // softmax (unnormalized p = exp2(s)); mask bit for (t,quad,r) is
            // key = 32*(t>>1) + 8*quad + 4*(t&1) + r of the 64-bit tile mask.
            const unsigned aw0 = w0 >> (quad * 8);   // t=0 (lo nibble) / t=1 (hi)
            const unsigned aw1 = w1 >> (quad * 8);   // t=2 / t=3
            union { s16x8 v; __hip_bfloat162 h2[4]; } pk0, pk1;
#pragma unroll
            for (int t = 0; t < 4; ++t) {
                const unsigned aw = ((t < 2) ? aw0 : aw1) >> ((t & 1) * 4);
                float p0 = __builtin_amdgcn_exp2f(((aw >> 0) & 1u) ? s[t][0] : -1e9f);
                float p1 = __builtin_amdgcn_exp2f(((aw >> 1) & 1u) ? s[t][1] : -1e9f);
                float p2 = __builtin_amdgcn_exp2f(((aw >> 2) & 1u) ? s[t][2] : -1e9f);
                float p3 = __builtin_amdgcn_exp2f(((aw >> 3) & 1u) ? s[t][3] : -1e9f);
                __hip_bfloat162 lo = __float22bfloat162_rn(float2{p0, p1});
                __hip_bfloat162 hi = __float22bfloat162_rn(float2{p2, p3});
                if      (t == 0) { pk0.h2[0] = lo; pk0.h2[1] = hi; }
                else if (t == 1) { pk0.h2[2] = lo; pk0.h2[3] = hi; }
                else if (t == 2) { pk1.h2[0] = lo; pk1.h2[1] = hi; }
                else             { pk1.h2[2] = lo; pk1.h2[3] = hi; }
            }

            // PV + ones-sum: P is already the A-fragment, fully in-register.
            __builtin_amdgcn_s_setprio(1);
#pragma unroll
            for (int half = 0; half < 2; ++half) {
                const s16x8 pa = half ? pk1.v : pk0.v;
#pragma unroll
                for (int c = 0; c < 4; ++c) {
                    const int vidx = (half ? (fbase ^ 32) : fbase) + c * 1024;
                    s16x8 vb = *(const s16x8*)(&Vt[u][vidx]);
                    acc[c] = __builtin_amdgcn_mfma_f32_16x16x32_bf16(pa, vb, acc[c], 0, 0, 0);
                }
                sum = __builtin_amdgcn_mfma_f32_16x16x32_bf16(pa, onesb, sum, 0, 0, 0);
            }
            __builtin_amdgcn_s_setprio(0);
        }
        mw = mw_nxt;
    }

    // epilogue: row sums are lane-local (ones-trick), no shuffles needed
#pragma unroll
    for (int r = 0; r < 4; ++r) {
        const float inv = 1.0f / sum[r];
        const size_t obase = head_off + (size_t)(qb + quad * 4 + r) * C_;
        O[obase + l16]      = acc[0][r] * inv;
        O[obase + l16 + 16] = acc[1][r] * inv;
        O[obase + l16 + 32] = acc[2][r] * inv;
        O[obase + l16 + 48] = acc[3][r] * inv;
    }
}

// ================== fallback (R6 verbatim): used if ws_size too small =========
#define KSTR 72
#define VSTR 72
__global__ __launch_bounds__(512, 4)
void mha_fwd_fb(const float* __restrict__ Q, const float* __restrict__ K,
                const float* __restrict__ V, const unsigned* __restrict__ bits,
                float* __restrict__ O) {
    __shared__ ushort Kl[2][KT * KSTR];
    __shared__ ushort Vt[2][HD_ * VSTR];
    __shared__ ushort Pl[NW][16 * PSTR];
    const int qt = blockIdx.x, h = blockIdx.y, b = blockIdx.z, tid = threadIdx.x;
    const int w = tid >> 6, lane = tid & 63, l16 = lane & 15, quad = lane >> 4;
    const size_t head_off = (size_t)b * N_ * C_ + (size_t)h * HD_;
    const int qb = qt * QB + w * 16;
    const float qs = 0.125f * 1.44269504088896f;
    const size_t qoff = head_off + (size_t)(qb + l16) * C_ + quad * 8;
    float4 q0 = *(const float4*)(Q + qoff);
    float4 q1 = *(const float4*)(Q + qoff + 4);
    float4 q2 = *(const float4*)(Q + qoff + 32);
    float4 q3 = *(const float4*)(Q + qoff + 36);
    q0.x*=qs; q0.y*=qs; q0.z*=qs; q0.w*=qs;
    q1.x*=qs; q1.y*=qs; q1.z*=qs; q1.w*=qs;
    q2.x*=qs; q2.y*=qs; q2.z*=qs; q2.w*=qs;
    q3.x*=qs; q3.y*=qs; q3.z*=qs; q3.w*=qs;
    const s16x8 qa0 = cvt8(q0, q1);
    const s16x8 qa1 = cvt8(q2, q3);
    f32x4 acc[4];
#pragma unroll
    for (int c = 0; c < 4; ++c) acc[c] = f32x4{0.f, 0.f, 0.f, 0.f};
    float lsum = 0.f;
    const int skey = tid >> 3, sd0 = (tid & 7) * 8;
    const int kp = tid >> 4, vd0 = (tid & 15) * 4;
    const int vcol = 2 * (kp & 3) + ((((kp >> 2) ^ (vd0 >> 3)) & 7) << 3);
    const unsigned* brow = bits + ((size_t)b * N_ + qb + l16) * (N_ / 32);
    const float SHIFT = 16.0f;
    {
        const size_t kbase = head_off + (size_t)skey * C_ + sd0;
        float4 kA = *(const float4*)(K + kbase);
        float4 kB = *(const float4*)(K + kbase + 4);
        *(s16x8*)(&Kl[0][skey * KSTR + sd0]) = cvt8(kA, kB);
        const size_t vbase = head_off + (size_t)(2 * kp) * C_ + vd0;
        float4 vA = *(const float4*)(V + vbase);
        float4 vB = *(const float4*)(V + vbase + C_);
        const float* ap = (const float*)&vA;
        const float* bp = (const float*)&vB;
#pragma unroll
        for (int i = 0; i < 4; ++i) {
            __hip_bfloat162 pr = __float22bfloat162_rn(float2{ap[i], bp[i]});
            *(unsigned*)(&Vt[0][(vd0 + i) * VSTR + vcol]) = *(unsigned*)&pr;
        }
    }
    for (int kt = 0; kt < NT; ++kt) {
        const int cur = kt & 1;
        float4 kA, kB, vA, vB;
        const bool has_next = (kt + 1 < NT);
        if (has_next) {
            const size_t kbase = head_off + (size_t)((kt + 1) * KT + skey) * C_ + sd0;
            kA = *(const float4*)(K + kbase);
            kB = *(const float4*)(K + kbase + 4);
            const size_t vbase = head_off + (size_t)((kt + 1) * KT + 2 * kp) * C_ + vd0;
            vA = *(const float4*)(V + vbase);
            vB = *(const float4*)(V + vbase + C_);
        }
        const unsigned w0 = brow[2 * kt];
        const unsigned w1 = brow[2 * kt + 1];
        __syncthreads();
        f32x4 s[4];
#pragma unroll
        for (int t = 0; t < 4; ++t) {
            s16x8 kb0 = *(const s16x8*)(&Kl[cur][(t * 16 + l16) * KSTR + quad * 8]);
            s16x8 kb1 = *(const s16x8*)(&Kl[cur][(t * 16 + l16) * KSTR + quad * 8 + 32]);
            f32x4 z = {0.f, 0.f, 0.f, 0.f};
            z = __builtin_amdgcn_mfma_f32_16x16x32_bf16(kb0, qa0, z, 0, 0, 0);
            z = __builtin_amdgcn_mfma_f32_16x16x32_bf16(kb1, qa1, z, 0, 0, 0);
            s[t] = z;
        }
        const unsigned a0 = w0 >> (quad * 4);
        const unsigned a1 = w1 >> (quad * 4);
#pragma unroll
        for (int t = 0; t < 4; ++t) {
            const unsigned aw = (t < 2) ? a0 : a1;
            const int sh = (t & 1) * 16;
            float p0 = exp2f((((aw >> (sh + 0)) & 1u) ? s[t][0] : -1e9f) - SHIFT);
            float p1 = exp2f((((aw >> (sh + 1)) & 1u) ? s[t][1] : -1e9f) - SHIFT);
            float p2 = exp2f((((aw >> (sh + 2)) & 1u) ? s[t][2] : -1e9f) - SHIFT);
            float p3 = exp2f((((aw >> (sh + 3)) & 1u) ? s[t][3] : -1e9f) - SHIFT);
            lsum += (p0 + p1) + (p2 + p3);
            union { s16x4 v; __hip_bfloat162 h2[2]; } uu;
            uu.h2[0] = __float22bfloat162_rn(float2{p0, p1});
            uu.h2[1] = __float22bfloat162_rn(float2{p2, p3});
            *(s16x4*)(&Pl[w][l16 * PSTR + t * 16 + quad * 4]) = uu.v;
        }
#pragma unroll
        for (int half = 0; half < 2; ++half) {
            s16x8 pa = *(const s16x8*)(&Pl[w][l16 * PSTR + half * 32 + quad * 8]);
#pragma unroll
            for (int c = 0; c < 4; ++c) {
                const int dr = c * 16 + l16;
                const int blk = (half * 4 + quad) ^ ((dr >> 3) & 7);
                s16x8 vb = *(const s16x8*)(&Vt[cur][dr * VSTR + blk * 8]);
                acc[c] = __builtin_amdgcn_mfma_f32_16x16x32_bf16(pa, vb, acc[c], 0, 0, 0);
            }
        }
        if (has_next) {
            *(s16x8*)(&Kl[1 - cur][skey * KSTR + sd0]) = cvt8(kA, kB);
            const float* ap = (const float*)&vA;
            const float* bp = (const float*)&vB;
#pragma unroll
            for (int i = 0; i < 4; ++i) {
                __hip_bfloat162 pr = __float22bfloat162_rn(float2{ap[i], bp[i]});
                *(unsigned*)(&Vt[1 - cur][(vd0 + i) * VSTR + vcol]) = *(unsigned*)&pr;
            }
        }
    }
    lsum += __shfl_xor(lsum, 16);
    lsum += __shfl_xor(lsum, 32);
#pragma unroll
    for (int r = 0; r < 4; ++r) {
        const float inv = 1.0f / __shfl(lsum, quad * 4 + r);
        const size_t obase = head_off + (size_t)(qb + quad * 4 + r) * C_;
        O[obase + l16]      = acc[0][r] * inv;
        O[obase + l16 + 16] = acc[1][r] * inv;
        O[obase + l16 + 32] = acc[2][r] * inv;
        O[obase + l16 + 48] = acc[3][r] * inv;
    }
}

extern "C" void kernel_launch(void* const* d_in, const int* in_sizes, int n_in,
                              void* d_out, int out_size, void* d_ws, size_t ws_size,
                              hipStream_t stream) {
    const float* q = (const float*)d_in[0];
    const float* k = (const float*)d_in[1];
    const float* v = (const float*)d_in[2];
    const int*   m = (const int*)d_in[3];
    float*       o = (float*)d_out;

    const size_t BITS_BYTES = (size_t)B_ * N_ * N_ / 8;          // 1 MiB
    const size_t KV_BYTES   = (size_t)B_ * H_ * N_ * HD_ * 2;    // 8.39 MB each
    const size_t NEED       = BITS_BYTES + 2 * KV_BYTES;

    unsigned long long* bits = (unsigned long long*)d_ws;

    if (ws_size >= NEED) {
        ushort* kw = (ushort*)((char*)d_ws + BITS_BYTES);
        ushort* vw = (ushort*)((char*)d_ws + BITS_BYTES + KV_BYTES);
        hipLaunchKernelGGL(prepass, dim3(4608), dim3(256), 0, stream,
                           m, k, v, bits, kw, vw);
        hipLaunchKernelGGL(mha_fwd, dim3(512), dim3(512), 0, stream,
                           q, kw, vw, (const unsigned*)bits, o);
    } else {
        hipLaunchKernelGGL(pack_mask, dim3(2048), dim3(256), 0, stream, m, bits);
        dim3 grid(N_ / QB, H_, B_);
        hipLaunchKernelGGL(mha_fwd_fb, grid, dim3(512), 0, stream,
                           q, k, v, (const unsigned*)bits, o);
    }
}

// Round 14
// 160.641 us; speedup vs baseline: 1.0245x; 1.0128x over previous
//
#include <hip/hip_runtime.h>
#include <hip/hip_bf16.h>

#define B_ 2
#define N_ 2048
#define C_ 1024
#define H_ 16
#define HD_ 64

#define KT 64            // key tile width per flash iteration
#define NT (N_ / KT)     // 32 tiles
#define TILE_E 4096      // elems per staged tile (64x64 bf16 = 8KB)
#define PSTR 72          // P LDS row stride (fallback kernel)
#define NW 8             // waves per block (fallback kernel)
#define QB 128           // q rows per block (fallback kernel)

#define NWM 8            // waves per block (main kernel: 512 threads)
#define QBM 128          // q rows per block (main: 16 per wave)

typedef short s16x8 __attribute__((ext_vector_type(8)));
typedef short s16x4 __attribute__((ext_vector_type(4)));
typedef float f32x4 __attribute__((ext_vector_type(4)));

__device__ __forceinline__ s16x8 cvt8(float4 a, float4 b) {
    union { s16x8 v; __hip_bfloat162 h[4]; } u;
    u.h[0] = __float22bfloat162_rn(float2{a.x, a.y});
    u.h[1] = __float22bfloat162_rn(float2{a.z, a.w});
    u.h[2] = __float22bfloat162_rn(float2{b.x, b.y});
    u.h[3] = __float22bfloat162_rn(float2{b.z, b.w});
    return u.v;
}

// async 16B/lane global -> LDS (DMA, no VGPR round trip)
__device__ __forceinline__ void gll16(const void* g, void* l) {
    __builtin_amdgcn_global_load_lds(
        (const __attribute__((address_space(1))) unsigned*)g,
        (__attribute__((address_space(3))) unsigned*)l, 16, 0, 0);
}

// ---- standalone pack_mask kept for the fallback path only
__global__ __launch_bounds__(256)
void pack_mask(const int* __restrict__ M, unsigned long long* __restrict__ bits) {
    const int gw   = (blockIdx.x * 256 + threadIdx.x) >> 6;
    const int lane = threadIdx.x & 63;
#pragma unroll
    for (int it = 0; it < 16; ++it) {
        const size_t wi = (size_t)gw * 16 + it;
        unsigned long long bal = __ballot(M[wi * 64 + lane] != 0);
        if (lane == 0) bits[wi] = bal;
    }
}

// ---- fused prepass: mask pack (blocks 0..2047), conv_k (2048..4095),
//      conv_v (4096..4607).
__global__ __launch_bounds__(256)
void prepass(const int* __restrict__ M, const float* __restrict__ K,
             const float* __restrict__ V, unsigned long long* __restrict__ bits,
             ushort* __restrict__ Kw, ushort* __restrict__ Vw) {
    const int bid = blockIdx.x;
    const int tid = threadIdx.x;
    if (bid < 2048) {
        // vectorized mask pack: 16 ints/thread (4x int4 = 64B), 1 ushort out.
        const int gt = bid * 256 + tid;            // 0..524287
        const int4* src = (const int4*)M + (size_t)gt * 4;
        unsigned r = 0;
#pragma unroll
        for (int c = 0; c < 4; ++c) {
            const int4 m4 = src[c];
            r |= (m4.x != 0 ? 1u : 0u) << (c * 4 + 0);
            r |= (m4.y != 0 ? 1u : 0u) << (c * 4 + 1);
            r |= (m4.z != 0 ? 1u : 0u) << (c * 4 + 2);
            r |= (m4.w != 0 ? 1u : 0u) << (c * 4 + 3);
        }
        ((ushort*)bits)[gt] = (ushort)r;
    } else if (bid < 4096) {
        // K fp32 -> bf16, tile-major, KEY-PERMUTED rows (aligns QK^T output
        // layout with the PV A-fragment layout so P stays in registers),
        // d-block XOR swizzle baked in.
        // perm: tile row p for key k: p5=k5, p4=k2, p3p2=k4k3, p1p0=k1k0
        const int gt = (bid - 2048) * 256 + tid;
        const int b  = gt >> 18;
        const int h  = (gt >> 14) & 15;
        const int n  = (gt >> 3) & 2047;
        const int db = gt & 7;
        const size_t src = (size_t)(b * N_ + n) * C_ + h * 64 + db * 8;
        float4 f0 = *(const float4*)(K + src);
        float4 f1 = *(const float4*)(K + src + 4);
        const int key = n & 63, kt = n >> 6;
        const int p = (key & 32) | ((key & 4) << 2) | ((key >> 1) & 12) | (key & 3);
        ushort* dst = Kw + (size_t)((b * H_ + h) * NT + kt) * TILE_E
                         + p * 64 + ((db ^ (p & 7)) * 8);
        *(s16x8*)dst = cvt8(f0, f1);
    } else {
        // V fp32 -> bf16 TRANSPOSED, tile-major, TRUE key order,
        // key-block XOR swizzle.
        const int gt  = (bid - 4096) * 256 + tid;
        const int b   = gt >> 16;
        const int h   = (gt >> 12) & 15;
        const int kt  = (gt >> 7) & 31;
        const int kb4 = (gt >> 3) & 15;
        const int db  = gt & 7;
        const int key0 = kb4 * 4;
        float f[4][8];
#pragma unroll
        for (int i = 0; i < 4; ++i) {
            const size_t src = (size_t)(b * N_ + kt * 64 + key0 + i) * C_ + h * 64 + db * 8;
            *(float4*)&f[i][0] = *(const float4*)(V + src);
            *(float4*)&f[i][4] = *(const float4*)(V + src + 4);
        }
        ushort* tb = Vw + (size_t)((b * H_ + h) * NT + kt) * TILE_E;
#pragma unroll
        for (int j = 0; j < 8; ++j) {
            const int d = db * 8 + j;
            union { s16x4 v; __hip_bfloat162 h2[2]; } u;
            u.h2[0] = __float22bfloat162_rn(float2{f[0][j], f[1][j]});
            u.h2[1] = __float22bfloat162_rn(float2{f[2][j], f[3][j]});
            *(s16x4*)(tb + d * 64 + (((key0 >> 3) ^ (d & 7)) * 8) + (key0 & 7)) = u.v;
        }
    }
}

// ---- main: R11 compute structure (512 threads, 8 waves, shared staging DMA,
//      16 q/wave, in-register P, ones-trick sums, setprio) with 4 LDS tile
//      buffers and ONE barrier per subtile-PAIR (16 barriers vs 32): waves
//      get ~2 subtiles of drift room so per-pipe bursts smooth out.
__global__ __launch_bounds__(512, 2)
void mha_fwd(const float* __restrict__ Q, const ushort* __restrict__ Kw,
             const ushort* __restrict__ Vw, const unsigned* __restrict__ bits,
             float* __restrict__ O) {
    __shared__ ushort Kl[4][TILE_E];       // 32 KB
    __shared__ ushort Vt[4][TILE_E];       // 32 KB  -> 65536 B total

    // XCD-aware bijective decode: xcd = sid&7 owns heads 4*xcd..4*xcd+3
    const int sid = blockIdx.x;            // 0..511
    const int jj  = sid >> 3;              // 0..63
    const int hb  = ((sid & 7) << 2) | (jj & 3);   // 0..31 = b*16+h
    const int qt  = jj >> 2;                        // 0..15
    const int h   = hb & 15;
    const int b   = hb >> 4;

    const int tid  = threadIdx.x;          // 0..511
    const int w    = tid >> 6;             // wave 0..7
    const int lane = tid & 63;
    const int l16  = lane & 15;
    const int quad = lane >> 4;

    const size_t head_off = (size_t)b * N_ * C_ + (size_t)h * HD_;
    const int qb = qt * QBM + w * 16;

    // Q fragment (B-operand of S^T = K Q^T); fold 1/8*log2(e): log2-domain
    const float qs = 0.125f * 1.44269504088896f;
    const size_t qoff = head_off + (size_t)(qb + l16) * C_ + quad * 8;
    float4 q0 = *(const float4*)(Q + qoff);
    float4 q1 = *(const float4*)(Q + qoff + 4);
    float4 q2 = *(const float4*)(Q + qoff + 32);
    float4 q3 = *(const float4*)(Q + qoff + 36);
    q0.x*=qs; q0.y*=qs; q0.z*=qs; q0.w*=qs;
    q1.x*=qs; q1.y*=qs; q1.z*=qs; q1.w*=qs;
    q2.x*=qs; q2.y*=qs; q2.z*=qs; q2.w*=qs;
    q3.x*=qs; q3.y*=qs; q3.z*=qs; q3.w*=qs;
    const s16x8 qa0 = cvt8(q0, q1);
    const s16x8 qa1 = cvt8(q2, q3);

    // constant all-ones bf16 B-fragment: row-sum via MFMA (ones-trick)
    s16x8 onesb;
#pragma unroll
    for (int i = 0; i < 8; ++i) onesb[i] = (short)0x3F80;

    // loop-invariant zero C-tuple: avoids re-zeroing z each subtile
    const f32x4 kZero = {0.f, 0.f, 0.f, 0.f};

    f32x4 acc[4];
#pragma unroll
    for (int c = 0; c < 4; ++c) acc[c] = f32x4{0.f, 0.f, 0.f, 0.f};
    f32x4 sum = f32x4{0.f, 0.f, 0.f, 0.f};

    // hoisted fragment element base (loop-invariant)
    const int fbase = l16 * 64 + ((quad ^ (l16 & 7)) * 8);

    // staging pointers: 512 threads cover an 8KB tile in ONE 16B/lane round
    const size_t tilebase = (size_t)((b * H_ + h) * NT) * TILE_E;
    const ushort* Kg = Kw + tilebase + (size_t)tid * 8;
    const ushort* Vg = Vw + tilebase + (size_t)tid * 8;

    const unsigned* mq = bits + ((size_t)b * N_ + qb + l16) * (N_ / 32);

    // prologue: stage tiles 0 and 1 into buffers 0 and 1
    gll16(Kg,          &Kl[0][w * 512]);
    gll16(Vg,          &Vt[0][w * 512]);
    gll16(Kg + TILE_E, &Kl[1][w * 512]);
    gll16(Vg + TILE_E, &Vt[1][w * 512]);
    const ushort* Kg_pf = Kg + 2 * TILE_E;
    const ushort* Vg_pf = Vg + 2 * TILE_E;

    uint4 mw = *(const uint4*)mq;  mq += 4;   // mask words for first tile pair

    for (int kt2 = 0; kt2 < NT; kt2 += 2) {
        const bool pf1 = (kt2 + 2 < NT);
        // prefetch next pair's mask words (guarded: never reads past bits)
        uint4 mw_nxt = mw;
        if (pf1) { mw_nxt = *(const uint4*)mq; }
        mq += 4;

        // ONE barrier per pair: tiles kt2, kt2+1 staged; buffers
        // (kt2+2)&3, (kt2+3)&3 were fully consumed before this barrier.
        __syncthreads();
        if (pf1) {
            const int b2 = (kt2 + 2) & 3;
            const int b3 = (kt2 + 3) & 3;
            gll16(Kg_pf,          &Kl[b2][w * 512]);
            gll16(Vg_pf,          &Vt[b2][w * 512]);
            gll16(Kg_pf + TILE_E, &Kl[b3][w * 512]);
            gll16(Vg_pf + TILE_E, &Vt[b3][w * 512]);
            Kg_pf += 2 * TILE_E;  Vg_pf += 2 * TILE_E;
        }

#pragma unroll
        for (int u = 0; u < 2; ++u) {        // two subtiles, no barrier between
            const ushort* Kb = &Kl[(kt2 + u) & 3][0];
            const ushort* Vb = &Vt[(kt2 + u) & 3][0];
            const unsigned w0 = u ? mw.z : mw.x;
            const unsigned w1 = u ? mw.w : mw.y;

            // S^T = K Q^T on the PERMUTED key rows: position (t,quad,r) holds
            // key 32*(t>>1) + 8*quad + 4*(t&1) + r  == PV A-fragment order.
            f32x4 s[4];
            __builtin_amdgcn_s_setprio(1);
#pragma unroll
            for (int t = 0; t < 4; ++t) {
                s16x8 kb0 = *(const s16x8*)(Kb + fbase + t * 1024);
                s16x8 kb1 = *(const s16x8*)(Kb + (fbase ^ 32) + t * 1024);
                f32x4 z = __builtin_amdgcn_mfma_f32_16x16x32_bf16(kb0, qa0, kZero, 0, 0, 0);
                z = __builtin_amdgcn_mfma_f32_16x16x32_bf16(kb1, qa1, z, 0, 0, 0);
                s[t] = z;
            }
            __builtin_amdgcn_s_setprio(0);

            // softmax (unnormalized p = exp2(s)); mask bit for (t,quad,r) is
            // key = 32*(t>>1) + 8*quad + 4*(t&1) + r of the 64-bit tile mask.
            const unsigned aw0 = w0 >> (quad * 8);   // t=0 (lo nibble) / t=1 (hi)
            const unsigned aw1 = w1 >> (quad * 8);   // t=2 / t=3
            union { s16x8 v; __hip_bfloat162 h2[4]; } pk0, pk1;
#pragma unroll
            for (int t = 0; t < 4; ++t) {
                const unsigned aw = ((t < 2) ? aw0 : aw1) >> ((t & 1) * 4);
                float p0 = __builtin_amdgcn_exp2f(((aw >> 0) & 1u) ? s[t][0] : -1e9f);
                float p1 = __builtin_amdgcn_exp2f(((aw >> 1) & 1u) ? s[t][1] : -1e9f);
                float p2 = __builtin_amdgcn_exp2f(((aw >> 2) & 1u) ? s[t][2] : -1e9f);
                float p3 = __builtin_amdgcn_exp2f(((aw >> 3) & 1u) ? s[t][3] : -1e9f);
                __hip_bfloat162 lo = __float22bfloat162_rn(float2{p0, p1});
                __hip_bfloat162 hi = __float22bfloat162_rn(float2{p2, p3});
                if      (t == 0) { pk0.h2[0] = lo; pk0.h2[1] = hi; }
                else if (t == 1) { pk0.h2[2] = lo; pk0.h2[3] = hi; }
                else if (t == 2) { pk1.h2[0] = lo; pk1.h2[1] = hi; }
                else             { pk1.h2[2] = lo; pk1.h2[3] = hi; }
            }

            // PV + ones-sum: P is already the A-fragment, fully in-register.
            __builtin_amdgcn_s_setprio(1);
#pragma unroll
            for (int half = 0; half < 2; ++half) {
                const s16x8 pa = half ? pk1.v : pk0.v;
#pragma unroll
                for (int c = 0; c < 4; ++c) {
                    const int vidx = (half ? (fbase ^ 32) : fbase) + c * 1024;
                    s16x8 vb = *(const s16x8*)(Vb + vidx);
                    acc[c] = __builtin_amdgcn_mfma_f32_16x16x32_bf16(pa, vb, acc[c], 0, 0, 0);
                }
                sum = __builtin_amdgcn_mfma_f32_16x16x32_bf16(pa, onesb, sum, 0, 0, 0);
            }
            __builtin_amdgcn_s_setprio(0);
        }
        mw = mw_nxt;
    }

    // epilogue: row sums are lane-local (ones-trick), no shuffles needed
#pragma unroll
    for (int r = 0; r < 4; ++r) {
        const float inv = 1.0f / sum[r];
        const size_t obase = head_off + (size_t)(qb + quad * 4 + r) * C_;
        O[obase + l16]      = acc[0][r] * inv;
        O[obase + l16 + 16] = acc[1][r] * inv;
        O[obase + l16 + 32] = acc[2][r] * inv;
        O[obase + l16 + 48] = acc[3][r] * inv;
    }
}

// ================== fallback (R6 verbatim): used if ws_size too small =========
#define KSTR 72
#define VSTR 72
__global__ __launch_bounds__(512, 4)
void mha_fwd_fb(const float* __restrict__ Q, const float* __restrict__ K,
                const float* __restrict__ V, const unsigned* __restrict__ bits,
                float* __restrict__ O) {
    __shared__ ushort Kl[2][KT * KSTR];
    __shared__ ushort Vt[2][HD_ * VSTR];
    __shared__ ushort Pl[NW][16 * PSTR];
    const int qt = blockIdx.x, h = blockIdx.y, b = blockIdx.z, tid = threadIdx.x;
    const int w = tid >> 6, lane = tid & 63, l16 = lane & 15, quad = lane >> 4;
    const size_t head_off = (size_t)b * N_ * C_ + (size_t)h * HD_;
    const int qb = qt * QB + w * 16;
    const float qs = 0.125f * 1.44269504088896f;
    const size_t qoff = head_off + (size_t)(qb + l16) * C_ + quad * 8;
    float4 q0 = *(const float4*)(Q + qoff);
    float4 q1 = *(const float4*)(Q + qoff + 4);
    float4 q2 = *(const float4*)(Q + qoff + 32);
    float4 q3 = *(const float4*)(Q + qoff + 36);
    q0.x*=qs; q0.y*=qs; q0.z*=qs; q0.w*=qs;
    q1.x*=qs; q1.y*=qs; q1.z*=qs; q1.w*=qs;
    q2.x*=qs; q2.y*=qs; q2.z*=qs; q2.w*=qs;
    q3.x*=qs; q3.y*=qs; q3.z*=qs; q3.w*=qs;
    const s16x8 qa0 = cvt8(q0, q1);
    const s16x8 qa1 = cvt8(q2, q3);
    f32x4 acc[4];
#pragma unroll
    for (int c = 0; c < 4; ++c) acc[c] = f32x4{0.f, 0.f, 0.f, 0.f};
    float lsum = 0.f;
    const int skey = tid >> 3, sd0 = (tid & 7) * 8;
    const int kp = tid >> 4, vd0 = (tid & 15) * 4;
    const int vcol = 2 * (kp & 3) + ((((kp >> 2) ^ (vd0 >> 3)) & 7) << 3);
    const unsigned* brow = bits + ((size_t)b * N_ + qb + l16) * (N_ / 32);
    const float SHIFT = 16.0f;
    {
        const size_t kbase = head_off + (size_t)skey * C_ + sd0;
        float4 kA = *(const float4*)(K + kbase);
        float4 kB = *(const float4*)(K + kbase + 4);
        *(s16x8*)(&Kl[0][skey * KSTR + sd0]) = cvt8(kA, kB);
        const size_t vbase = head_off + (size_t)(2 * kp) * C_ + vd0;
        float4 vA = *(const float4*)(V + vbase);
        float4 vB = *(const float4*)(V + vbase + C_);
        const float* ap = (const float*)&vA;
        const float* bp = (const float*)&vB;
#pragma unroll
        for (int i = 0; i < 4; ++i) {
            __hip_bfloat162 pr = __float22bfloat162_rn(float2{ap[i], bp[i]});
            *(unsigned*)(&Vt[0][(vd0 + i) * VSTR + vcol]) = *(unsigned*)&pr;
        }
    }
    for (int kt = 0; kt < NT; ++kt) {
        const int cur = kt & 1;
        float4 kA, kB, vA, vB;
        const bool has_next = (kt + 1 < NT);
        if (has_next) {
            const size_t kbase = head_off + (size_t)((kt + 1) * KT + skey) * C_ + sd0;
            kA = *(const float4*)(K + kbase);
            kB = *(const float4*)(K + kbase + 4);
            const size_t vbase = head_off + (size_t)((kt + 1) * KT + 2 * kp) * C_ + vd0;
            vA = *(const float4*)(V + vbase);
            vB = *(const float4*)(V + vbase + C_);
        }
        const unsigned w0 = brow[2 * kt];
        const unsigned w1 = brow[2 * kt + 1];
        __syncthreads();
        f32x4 s[4];
#pragma unroll
        for (int t = 0; t < 4; ++t) {
            s16x8 kb0 = *(const s16x8*)(&Kl[cur][(t * 16 + l16) * KSTR + quad * 8]);
            s16x8 kb1 = *(const s16x8*)(&Kl[cur][(t * 16 + l16) * KSTR + quad * 8 + 32]);
            f32x4 z = {0.f, 0.f, 0.f, 0.f};
            z = __builtin_amdgcn_mfma_f32_16x16x32_bf16(kb0, qa0, z, 0, 0, 0);
            z = __builtin_amdgcn_mfma_f32_16x16x32_bf16(kb1, qa1, z, 0, 0, 0);
            s[t] = z;
        }
        const unsigned a0 = w0 >> (quad * 4);
        const unsigned a1 = w1 >> (quad * 4);
#pragma unroll
        for (int t = 0; t < 4; ++t) {
            const unsigned aw = (t < 2) ? a0 : a1;
            const int sh = (t & 1) * 16;
            float p0 = exp2f((((aw >> (sh + 0)) & 1u) ? s[t][0] : -1e9f) - SHIFT);
            float p1 = exp2f((((aw >> (sh + 1)) & 1u) ? s[t][1] : -1e9f) - SHIFT);
            float p2 = exp2f((((aw >> (sh + 2)) & 1u) ? s[t][2] : -1e9f) - SHIFT);
            float p3 = exp2f((((aw >> (sh + 3)) & 1u) ? s[t][3] : -1e9f) - SHIFT);
            lsum += (p0 + p1) + (p2 + p3);
            union { s16x4 v; __hip_bfloat162 h2[2]; } uu;
            uu.h2[0] = __float22bfloat162_rn(float2{p0, p1});
            uu.h2[1] = __float22bfloat162_rn(float2{p2, p3});
            *(s16x4*)(&Pl[w][l16 * PSTR + t * 16 + quad * 4]) = uu.v;
        }
#pragma unroll
        for (int half = 0; half < 2; ++half) {
            s16x8 pa = *(const s16x8*)(&Pl[w][l16 * PSTR + half * 32 + quad * 8]);
#pragma unroll
            for (int c = 0; c < 4; ++c) {
                const int dr = c * 16 + l16;
                const int blk = (half * 4 + quad) ^ ((dr >> 3) & 7);
                s16x8 vb = *(const s16x8*)(&Vt[cur][dr * VSTR + blk * 8]);
                acc[c] = __builtin_amdgcn_mfma_f32_16x16x32_bf16(pa, vb, acc[c], 0, 0, 0);
            }
        }
        if (has_next) {
            *(s16x8*)(&Kl[1 - cur][skey * KSTR + sd0]) = cvt8(kA, kB);
            const float* ap = (const float*)&vA;
            const float* bp = (const float*)&vB;
#pragma unroll
            for (int i = 0; i < 4; ++i) {
                __hip_bfloat162 pr = __float22bfloat162_rn(float2{ap[i], bp[i]});
                *(unsigned*)(&Vt[1 - cur][(vd0 + i) * VSTR + vcol]) = *(unsigned*)&pr;
            }
        }
    }
    lsum += __shfl_xor(lsum, 16);
    lsum += __shfl_xor(lsum, 32);
#pragma unroll
    for (int r = 0; r < 4; ++r) {
        const float inv = 1.0f / __shfl(lsum, quad * 4 + r);
        const size_t obase = head_off + (size_t)(qb + quad * 4 + r) * C_;
        O[obase + l16]      = acc[0][r] * inv;
        O[obase + l16 + 16] = acc[1][r] * inv;
        O[obase + l16 + 32] = acc[2][r] * inv;
        O[obase + l16 + 48] = acc[3][r] * inv;
    }
}

extern "C" void kernel_launch(void* const* d_in, const int* in_sizes, int n_in,
                              void* d_out, int out_size, void* d_ws, size_t ws_size,
                              hipStream_t stream) {
    const float* q = (const float*)d_in[0];
    const float* k = (const float*)d_in[1];
    const float* v = (const float*)d_in[2];
    const int*   m = (const int*)d_in[3];
    float*       o = (float*)d_out;

    const size_t BITS_BYTES = (size_t)B_ * N_ * N_ / 8;          // 1 MiB
    const size_t KV_BYTES   = (size_t)B_ * H_ * N_ * HD_ * 2;    // 8.39 MB each
    const size_t NEED       = BITS_BYTES + 2 * KV_BYTES;

    unsigned long long* bits = (unsigned long long*)d_ws;

    if (ws_size >= NEED) {
        ushort* kw = (ushort*)((char*)d_ws + BITS_BYTES);
        ushort* vw = (ushort*)((char*)d_ws + BITS_BYTES + KV_BYTES);
        hipLaunchKernelGGL(prepass, dim3(4608), dim3(256), 0, stream,
                           m, k, v, bits, kw, vw);
        hipLaunchKernelGGL(mha_fwd, dim3(512), dim3(512), 0, stream,
                           q, kw, vw, (const unsigned*)bits, o);
    } else {
        hipLaunchKernelGGL(pack_mask, dim3(2048), dim3(256), 0, stream, m, bits);
        dim3 grid(N_ / QB, H_, B_);
        hipLaunchKernelGGL(mha_fwd_fb, grid, dim3(512), 0, stream,
                           q, k, v, (const unsigned*)bits, o);
    }
}

// Round 15
// 159.760 us; speedup vs baseline: 1.0301x; 1.0055x over previous
//
#include <hip/hip_runtime.h>
#include <hip/hip_bf16.h>

#define B_ 2
#define N_ 2048
#define C_ 1024
#define H_ 16
#define HD_ 64

#define KT 64            // key tile width per flash iteration
#define NT (N_ / KT)     // 32 tiles
#define TILE_E 4096      // elems per staged tile (64x64 bf16 = 8KB)
#define PSTR 72          // P LDS row stride (fallback kernel)
#define NW 8             // waves per block (fallback kernel)
#define QB 128           // q rows per block (fallback kernel)

#define NWM 16           // waves per block (main kernel: 1024 threads)
#define QBM 256          // q rows per block (main: 16 per wave)

typedef short s16x8 __attribute__((ext_vector_type(8)));
typedef short s16x4 __attribute__((ext_vector_type(4)));
typedef float f32x4 __attribute__((ext_vector_type(4)));

__device__ __forceinline__ s16x8 cvt8(float4 a, float4 b) {
    union { s16x8 v; __hip_bfloat162 h[4]; } u;
    u.h[0] = __float22bfloat162_rn(float2{a.x, a.y});
    u.h[1] = __float22bfloat162_rn(float2{a.z, a.w});
    u.h[2] = __float22bfloat162_rn(float2{b.x, b.y});
    u.h[3] = __float22bfloat162_rn(float2{b.z, b.w});
    return u.v;
}

// async 16B/lane global -> LDS (DMA, no VGPR round trip)
__device__ __forceinline__ void gll16(const void* g, void* l) {
    __builtin_amdgcn_global_load_lds(
        (const __attribute__((address_space(1))) unsigned*)g,
        (__attribute__((address_space(3))) unsigned*)l, 16, 0, 0);
}

// ---- standalone pack_mask kept for the fallback path only
__global__ __launch_bounds__(256)
void pack_mask(const int* __restrict__ M, unsigned long long* __restrict__ bits) {
    const int gw   = (blockIdx.x * 256 + threadIdx.x) >> 6;
    const int lane = threadIdx.x & 63;
#pragma unroll
    for (int it = 0; it < 16; ++it) {
        const size_t wi = (size_t)gw * 16 + it;
        unsigned long long bal = __ballot(M[wi * 64 + lane] != 0);
        if (lane == 0) bits[wi] = bal;
    }
}

// ---- fused prepass: mask pack (blocks 0..2047), conv_k (2048..4095),
//      conv_v (4096..4607).
__global__ __launch_bounds__(256)
void prepass(const int* __restrict__ M, const float* __restrict__ K,
             const float* __restrict__ V, unsigned long long* __restrict__ bits,
             ushort* __restrict__ Kw, ushort* __restrict__ Vw) {
    const int bid = blockIdx.x;
    const int tid = threadIdx.x;
    if (bid < 2048) {
        // vectorized mask pack: 16 ints/thread (4x int4 = 64B), 1 ushort out.
        const int gt = bid * 256 + tid;            // 0..524287
        const int4* src = (const int4*)M + (size_t)gt * 4;
        unsigned r = 0;
#pragma unroll
        for (int c = 0; c < 4; ++c) {
            const int4 m4 = src[c];
            r |= (m4.x != 0 ? 1u : 0u) << (c * 4 + 0);
            r |= (m4.y != 0 ? 1u : 0u) << (c * 4 + 1);
            r |= (m4.z != 0 ? 1u : 0u) << (c * 4 + 2);
            r |= (m4.w != 0 ? 1u : 0u) << (c * 4 + 3);
        }
        ((ushort*)bits)[gt] = (ushort)r;
    } else if (bid < 4096) {
        // K fp32 -> bf16, tile-major, KEY-PERMUTED rows (aligns QK^T output
        // layout with the PV A-fragment layout so P stays in registers),
        // d-block XOR swizzle baked in.
        // perm: tile row p for key k: p5=k5, p4=k2, p3p2=k4k3, p1p0=k1k0
        const int gt = (bid - 2048) * 256 + tid;
        const int b  = gt >> 18;
        const int h  = (gt >> 14) & 15;
        const int n  = (gt >> 3) & 2047;
        const int db = gt & 7;
        const size_t src = (size_t)(b * N_ + n) * C_ + h * 64 + db * 8;
        float4 f0 = *(const float4*)(K + src);
        float4 f1 = *(const float4*)(K + src + 4);
        const int key = n & 63, kt = n >> 6;
        const int p = (key & 32) | ((key & 4) << 2) | ((key >> 1) & 12) | (key & 3);
        ushort* dst = Kw + (size_t)((b * H_ + h) * NT + kt) * TILE_E
                         + p * 64 + ((db ^ (p & 7)) * 8);
        *(s16x8*)dst = cvt8(f0, f1);
    } else {
        // V fp32 -> bf16 TRANSPOSED, tile-major, TRUE key order,
        // key-block XOR swizzle.
        const int gt  = (bid - 4096) * 256 + tid;
        const int b   = gt >> 16;
        const int h   = (gt >> 12) & 15;
        const int kt  = (gt >> 7) & 31;
        const int kb4 = (gt >> 3) & 15;
        const int db  = gt & 7;
        const int key0 = kb4 * 4;
        float f[4][8];
#pragma unroll
        for (int i = 0; i < 4; ++i) {
            const size_t src = (size_t)(b * N_ + kt * 64 + key0 + i) * C_ + h * 64 + db * 8;
            *(float4*)&f[i][0] = *(const float4*)(V + src);
            *(float4*)&f[i][4] = *(const float4*)(V + src + 4);
        }
        ushort* tb = Vw + (size_t)((b * H_ + h) * NT + kt) * TILE_E;
#pragma unroll
        for (int j = 0; j < 8; ++j) {
            const int d = db * 8 + j;
            union { s16x4 v; __hip_bfloat162 h2[2]; } u;
            u.h2[0] = __float22bfloat162_rn(float2{f[0][j], f[1][j]});
            u.h2[1] = __float22bfloat162_rn(float2{f[2][j], f[3][j]});
            *(s16x4*)(tb + d * 64 + (((key0 >> 3) ^ (d & 7)) * 8) + (key0 & 7)) = u.v;
        }
    }
}

// ---- main: 1024-thread blocks (16 waves, 256 q), grid 256 = 1 block/CU.
//      8-tile LDS ring (128 KB), ONE barrier per 4 subtiles (8 barriers).
//      Staging DMA issued once per CU per tile (2x dedup vs R14).
//      Per-wave compute identical to R14 (16 q/wave, in-register P,
//      ones-trick sums, setprio).
__global__ __launch_bounds__(1024, 1)
void mha_fwd(const float* __restrict__ Q, const ushort* __restrict__ Kw,
             const ushort* __restrict__ Vw, const unsigned* __restrict__ bits,
             float* __restrict__ O) {
    __shared__ ushort Kl[8][TILE_E];       // 64 KB
    __shared__ ushort Vt[8][TILE_E];       // 64 KB  -> 131072 B total

    // XCD-aware bijective decode: xcd = sid&7 owns heads 4*xcd..4*xcd+3
    const int sid = blockIdx.x;            // 0..255
    const int jj  = sid >> 3;              // 0..31
    const int hb  = ((sid & 7) << 2) | (jj & 3);   // 0..31 = b*16+h
    const int qt  = jj >> 2;                        // 0..7
    const int h   = hb & 15;
    const int b   = hb >> 4;

    const int tid  = threadIdx.x;          // 0..1023
    const int w    = tid >> 6;             // wave 0..15
    const int lane = tid & 63;
    const int l16  = lane & 15;
    const int quad = lane >> 4;

    const size_t head_off = (size_t)b * N_ * C_ + (size_t)h * HD_;
    const int qb = qt * QBM + w * 16;

    // Q fragment (B-operand of S^T = K Q^T); fold 1/8*log2(e): log2-domain
    const float qs = 0.125f * 1.44269504088896f;
    const size_t qoff = head_off + (size_t)(qb + l16) * C_ + quad * 8;
    float4 q0 = *(const float4*)(Q + qoff);
    float4 q1 = *(const float4*)(Q + qoff + 4);
    float4 q2 = *(const float4*)(Q + qoff + 32);
    float4 q3 = *(const float4*)(Q + qoff + 36);
    q0.x*=qs; q0.y*=qs; q0.z*=qs; q0.w*=qs;
    q1.x*=qs; q1.y*=qs; q1.z*=qs; q1.w*=qs;
    q2.x*=qs; q2.y*=qs; q2.z*=qs; q2.w*=qs;
    q3.x*=qs; q3.y*=qs; q3.z*=qs; q3.w*=qs;
    const s16x8 qa0 = cvt8(q0, q1);
    const s16x8 qa1 = cvt8(q2, q3);

    // constant all-ones bf16 B-fragment: row-sum via MFMA (ones-trick)
    s16x8 onesb;
#pragma unroll
    for (int i = 0; i < 8; ++i) onesb[i] = (short)0x3F80;

    // loop-invariant zero C-tuple: avoids re-zeroing z each subtile
    const f32x4 kZero = {0.f, 0.f, 0.f, 0.f};

    f32x4 acc[4];
#pragma unroll
    for (int c = 0; c < 4; ++c) acc[c] = f32x4{0.f, 0.f, 0.f, 0.f};
    f32x4 sum = f32x4{0.f, 0.f, 0.f, 0.f};

    // hoisted fragment element base (loop-invariant)
    const int fbase = l16 * 64 + ((quad ^ (l16 & 7)) * 8);

    // staging pointers: 1024 threads cover a 16KB TILE-PAIR in one
    // 16B/lane issue (LDS dest spans two adjacent ring slots).
    const size_t tilebase = (size_t)((b * H_ + h) * NT) * TILE_E;
    const ushort* Kg = Kw + tilebase + (size_t)tid * 8;
    const ushort* Vg = Vw + tilebase + (size_t)tid * 8;

    const unsigned* mq = bits + ((size_t)b * N_ + qb + l16) * (N_ / 32);

    // prologue: stage tiles 0..3 into ring slots 0..3 (2 pair-issues each)
    gll16(Kg,              &Kl[0][w * 512]);
    gll16(Kg + 2 * TILE_E, &Kl[2][w * 512]);
    gll16(Vg,              &Vt[0][w * 512]);
    gll16(Vg + 2 * TILE_E, &Vt[2][w * 512]);
    const ushort* Kg_pf = Kg + 4 * TILE_E;
    const ushort* Vg_pf = Vg + 4 * TILE_E;

    uint4 mA = *(const uint4*)mq;          // mask words tiles 0..1
    uint4 mB = *(const uint4*)(mq + 4);    // mask words tiles 2..3
    mq += 8;

    for (int kt4 = 0; kt4 < NT; kt4 += 4) {
        const bool pf = (kt4 + 4 < NT);
        // prefetch next group's mask words (guarded: never reads past bits)
        uint4 mA_n = mA, mB_n = mB;
        if (pf) { mA_n = *(const uint4*)mq; mB_n = *(const uint4*)(mq + 4); }
        mq += 8;

        // ONE barrier per 4 tiles: tiles kt4..kt4+3 staged; ring slots
        // (kt4+4..kt4+7)&7 fully consumed before this barrier.
        __syncthreads();
        if (pf) {
            const int s0 = (kt4 + 4) & 7;    // even pair base
            const int s2 = (kt4 + 6) & 7;
            gll16(Kg_pf,              &Kl[s0][w * 512]);
            gll16(Kg_pf + 2 * TILE_E, &Kl[s2][w * 512]);
            gll16(Vg_pf,              &Vt[s0][w * 512]);
            gll16(Vg_pf + 2 * TILE_E, &Vt[s2][w * 512]);
            Kg_pf += 4 * TILE_E;  Vg_pf += 4 * TILE_E;
        }

#pragma unroll
        for (int u = 0; u < 4; ++u) {        // four subtiles, no barrier between
            const ushort* Kb = &Kl[(kt4 + u) & 7][0];
            const ushort* Vb = &Vt[(kt4 + u) & 7][0];
            const unsigned w0 = (u == 0) ? mA.x : (u == 1) ? mA.z
                               : (u == 2) ? mB.x : mB.z;
            const unsigned w1 = (u == 0) ? mA.y : (u == 1) ? mA.w
                               : (u == 2) ? mB.y : mB.w;

            // S^T = K Q^T on the PERMUTED key rows: position (t,quad,r) holds
            // key 32*(t>>1) + 8*quad + 4*(t&1) + r  == PV A-fragment order.
            f32x4 s[4];
            __builtin_amdgcn_s_setprio(1);
#pragma unroll
            for (int t = 0; t < 4; ++t) {
                s16x8 kb0 = *(const s16x8*)(Kb + fbase + t * 1024);
                s16x8 kb1 = *(const s16x8*)(Kb + (fbase ^ 32) + t * 1024);
                f32x4 z = __builtin_amdgcn_mfma_f32_16x16x32_bf16(kb0, qa0, kZero, 0, 0, 0);
                z = __builtin_amdgcn_mfma_f32_16x16x32_bf16(kb1, qa1, z, 0, 0, 0);
                s[t] = z;
            }
            __builtin_amdgcn_s_setprio(0);

            // softmax (unnormalized p = exp2(s)); mask bit for (t,quad,r) is
            // key = 32*(t>>1) + 8*quad + 4*(t&1) + r of the 64-bit tile mask.
            const unsigned aw0 = w0 >> (quad * 8);   // t=0 (lo nibble) / t=1 (hi)
            const unsigned aw1 = w1 >> (quad * 8);   // t=2 / t=3
            union { s16x8 v; __hip_bfloat162 h2[4]; } pk0, pk1;
#pragma unroll
            for (int t = 0; t < 4; ++t) {
                const unsigned aw = ((t < 2) ? aw0 : aw1) >> ((t & 1) * 4);
                float p0 = __builtin_amdgcn_exp2f(((aw >> 0) & 1u) ? s[t][0] : -1e9f);
                float p1 = __builtin_amdgcn_exp2f(((aw >> 1) & 1u) ? s[t][1] : -1e9f);
                float p2 = __builtin_amdgcn_exp2f(((aw >> 2) & 1u) ? s[t][2] : -1e9f);
                float p3 = __builtin_amdgcn_exp2f(((aw >> 3) & 1u) ? s[t][3] : -1e9f);
                __hip_bfloat162 lo = __float22bfloat162_rn(float2{p0, p1});
                __hip_bfloat162 hi = __float22bfloat162_rn(float2{p2, p3});
                if      (t == 0) { pk0.h2[0] = lo; pk0.h2[1] = hi; }
                else if (t == 1) { pk0.h2[2] = lo; pk0.h2[3] = hi; }
                else if (t == 2) { pk1.h2[0] = lo; pk1.h2[1] = hi; }
                else             { pk1.h2[2] = lo; pk1.h2[3] = hi; }
            }

            // PV + ones-sum: P is already the A-fragment, fully in-register.
            __builtin_amdgcn_s_setprio(1);
#pragma unroll
            for (int half = 0; half < 2; ++half) {
                const s16x8 pa = half ? pk1.v : pk0.v;
#pragma unroll
                for (int c = 0; c < 4; ++c) {
                    const int vidx = (half ? (fbase ^ 32) : fbase) + c * 1024;
                    s16x8 vb = *(const s16x8*)(Vb + vidx);
                    acc[c] = __builtin_amdgcn_mfma_f32_16x16x32_bf16(pa, vb, acc[c], 0, 0, 0);
                }
                sum = __builtin_amdgcn_mfma_f32_16x16x32_bf16(pa, onesb, sum, 0, 0, 0);
            }
            __builtin_amdgcn_s_setprio(0);
        }
        mA = mA_n;  mB = mB_n;
    }

    // epilogue: row sums are lane-local (ones-trick), no shuffles needed
#pragma unroll
    for (int r = 0; r < 4; ++r) {
        const float inv = 1.0f / sum[r];
        const size_t obase = head_off + (size_t)(qb + quad * 4 + r) * C_;
        O[obase + l16]      = acc[0][r] * inv;
        O[obase + l16 + 16] = acc[1][r] * inv;
        O[obase + l16 + 32] = acc[2][r] * inv;
        O[obase + l16 + 48] = acc[3][r] * inv;
    }
}

// ================== fallback (R6 verbatim): used if ws_size too small =========
#define KSTR 72
#define VSTR 72
__global__ __launch_bounds__(512, 4)
void mha_fwd_fb(const float* __restrict__ Q, const float* __restrict__ K,
                const float* __restrict__ V, const unsigned* __restrict__ bits,
                float* __restrict__ O) {
    __shared__ ushort Kl[2][KT * KSTR];
    __shared__ ushort Vt[2][HD_ * VSTR];
    __shared__ ushort Pl[NW][16 * PSTR];
    const int qt = blockIdx.x, h = blockIdx.y, b = blockIdx.z, tid = threadIdx.x;
    const int w = tid >> 6, lane = tid & 63, l16 = lane & 15, quad = lane >> 4;
    const size_t head_off = (size_t)b * N_ * C_ + (size_t)h * HD_;
    const int qb = qt * QB + w * 16;
    const float qs = 0.125f * 1.44269504088896f;
    const size_t qoff = head_off + (size_t)(qb + l16) * C_ + quad * 8;
    float4 q0 = *(const float4*)(Q + qoff);
    float4 q1 = *(const float4*)(Q + qoff + 4);
    float4 q2 = *(const float4*)(Q + qoff + 32);
    float4 q3 = *(const float4*)(Q + qoff + 36);
    q0.x*=qs; q0.y*=qs; q0.z*=qs; q0.w*=qs;
    q1.x*=qs; q1.y*=qs; q1.z*=qs; q1.w*=qs;
    q2.x*=qs; q2.y*=qs; q2.z*=qs; q2.w*=qs;
    q3.x*=qs; q3.y*=qs; q3.z*=qs; q3.w*=qs;
    const s16x8 qa0 = cvt8(q0, q1);
    const s16x8 qa1 = cvt8(q2, q3);
    f32x4 acc[4];
#pragma unroll
    for (int c = 0; c < 4; ++c) acc[c] = f32x4{0.f, 0.f, 0.f, 0.f};
    float lsum = 0.f;
    const int skey = tid >> 3, sd0 = (tid & 7) * 8;
    const int kp = tid >> 4, vd0 = (tid & 15) * 4;
    const int vcol = 2 * (kp & 3) + ((((kp >> 2) ^ (vd0 >> 3)) & 7) << 3);
    const unsigned* brow = bits + ((size_t)b * N_ + qb + l16) * (N_ / 32);
    const float SHIFT = 16.0f;
    {
        const size_t kbase = head_off + (size_t)skey * C_ + sd0;
        float4 kA = *(const float4*)(K + kbase);
        float4 kB = *(const float4*)(K + kbase + 4);
        *(s16x8*)(&Kl[0][skey * KSTR + sd0]) = cvt8(kA, kB);
        const size_t vbase = head_off + (size_t)(2 * kp) * C_ + vd0;
        float4 vA = *(const float4*)(V + vbase);
        float4 vB = *(const float4*)(V + vbase + C_);
        const float* ap = (const float*)&vA;
        const float* bp = (const float*)&vB;
#pragma unroll
        for (int i = 0; i < 4; ++i) {
            __hip_bfloat162 pr = __float22bfloat162_rn(float2{ap[i], bp[i]});
            *(unsigned*)(&Vt[0][(vd0 + i) * VSTR + vcol]) = *(unsigned*)&pr;
        }
    }
    for (int kt = 0; kt < NT; ++kt) {
        const int cur = kt & 1;
        float4 kA, kB, vA, vB;
        const bool has_next = (kt + 1 < NT);
        if (has_next) {
            const size_t kbase = head_off + (size_t)((kt + 1) * KT + skey) * C_ + sd0;
            kA = *(const float4*)(K + kbase);
            kB = *(const float4*)(K + kbase + 4);
            const size_t vbase = head_off + (size_t)((kt + 1) * KT + 2 * kp) * C_ + vd0;
            vA = *(const float4*)(V + vbase);
            vB = *(const float4*)(V + vbase + C_);
        }
        const unsigned w0 = brow[2 * kt];
        const unsigned w1 = brow[2 * kt + 1];
        __syncthreads();
        f32x4 s[4];
#pragma unroll
        for (int t = 0; t < 4; ++t) {
            s16x8 kb0 = *(const s16x8*)(&Kl[cur][(t * 16 + l16) * KSTR + quad * 8]);
            s16x8 kb1 = *(const s16x8*)(&Kl[cur][(t * 16 + l16) * KSTR + quad * 8 + 32]);
            f32x4 z = {0.f, 0.f, 0.f, 0.f};
            z = __builtin_amdgcn_mfma_f32_16x16x32_bf16(kb0, qa0, z, 0, 0, 0);
            z = __builtin_amdgcn_mfma_f32_16x16x32_bf16(kb1, qa1, z, 0, 0, 0);
            s[t] = z;
        }
        const unsigned a0 = w0 >> (quad * 4);
        const unsigned a1 = w1 >> (quad * 4);
#pragma unroll
        for (int t = 0; t < 4; ++t) {
            const unsigned aw = (t < 2) ? a0 : a1;
            const int sh = (t & 1) * 16;
            float p0 = exp2f((((aw >> (sh + 0)) & 1u) ? s[t][0] : -1e9f) - SHIFT);
            float p1 = exp2f((((aw >> (sh + 1)) & 1u) ? s[t][1] : -1e9f) - SHIFT);
            float p2 = exp2f((((aw >> (sh + 2)) & 1u) ? s[t][2] : -1e9f) - SHIFT);
            float p3 = exp2f((((aw >> (sh + 3)) & 1u) ? s[t][3] : -1e9f) - SHIFT);
            lsum += (p0 + p1) + (p2 + p3);
            union { s16x4 v; __hip_bfloat162 h2[2]; } uu;
            uu.h2[0] = __float22bfloat162_rn(float2{p0, p1});
            uu.h2[1] = __float22bfloat162_rn(float2{p2, p3});
            *(s16x4*)(&Pl[w][l16 * PSTR + t * 16 + quad * 4]) = uu.v;
        }
#pragma unroll
        for (int half = 0; half < 2; ++half) {
            s16x8 pa = *(const s16x8*)(&Pl[w][l16 * PSTR + half * 32 + quad * 8]);
#pragma unroll
            for (int c = 0; c < 4; ++c) {
                const int dr = c * 16 + l16;
                const int blk = (half * 4 + quad) ^ ((dr >> 3) & 7);
                s16x8 vb = *(const s16x8*)(&Vt[cur][dr * VSTR + blk * 8]);
                acc[c] = __builtin_amdgcn_mfma_f32_16x16x32_bf16(pa, vb, acc[c], 0, 0, 0);
            }
        }
        if (has_next) {
            *(s16x8*)(&Kl[1 - cur][skey * KSTR + sd0]) = cvt8(kA, kB);
            const float* ap = (const float*)&vA;
            const float* bp = (const float*)&vB;
#pragma unroll
            for (int i = 0; i < 4; ++i) {
                __hip_bfloat162 pr = __float22bfloat162_rn(float2{ap[i], bp[i]});
                *(unsigned*)(&Vt[1 - cur][(vd0 + i) * VSTR + vcol]) = *(unsigned*)&pr;
            }
        }
    }
    lsum += __shfl_xor(lsum, 16);
    lsum += __shfl_xor(lsum, 32);
#pragma unroll
    for (int r = 0; r < 4; ++r) {
        const float inv = 1.0f / __shfl(lsum, quad * 4 + r);
        const size_t obase = head_off + (size_t)(qb + quad * 4 + r) * C_;
        O[obase + l16]      = acc[0][r] * inv;
        O[obase + l16 + 16] = acc[1][r] * inv;
        O[obase + l16 + 32] = acc[2][r] * inv;
        O[obase + l16 + 48] = acc[3][r] * inv;
    }
}

extern "C" void kernel_launch(void* const* d_in, const int* in_sizes, int n_in,
                              void* d_out, int out_size, void* d_ws, size_t ws_size,
                              hipStream_t stream) {
    const float* q = (const float*)d_in[0];
    const float* k = (const float*)d_in[1];
    const float* v = (const float*)d_in[2];
    const int*   m = (const int*)d_in[3];
    float*       o = (float*)d_out;

    const size_t BITS_BYTES = (size_t)B_ * N_ * N_ / 8;          // 1 MiB
    const size_t KV_BYTES   = (size_t)B_ * H_ * N_ * HD_ * 2;    // 8.39 MB each
    const size_t NEED       = BITS_BYTES + 2 * KV_BYTES;

    unsigned long long* bits = (unsigned long long*)d_ws;

    if (ws_size >= NEED) {
        ushort* kw = (ushort*)((char*)d_ws + BITS_BYTES);
        ushort* vw = (ushort*)((char*)d_ws + BITS_BYTES + KV_BYTES);
        hipLaunchKernelGGL(prepass, dim3(4608), dim3(256), 0, stream,
                           m, k, v, bits, kw, vw);
        hipLaunchKernelGGL(mha_fwd, dim3(256), dim3(1024), 0, stream,
                           q, kw, vw, (const unsigned*)bits, o);
    } else {
        hipLaunchKernelGGL(pack_mask, dim3(2048), dim3(256), 0, stream, m, bits);
        dim3 grid(N_ / QB, H_, B_);
        hipLaunchKernelGGL(mha_fwd_fb, grid, dim3(512), 0, stream,
                           q, k, v, (const unsigned*)bits, o);
    }
}